// Round 8
// baseline (173.513 us; speedup 1.0000x reference)
//
#include <hip/hip_runtime.h>
#include <math.h>

// Problem constants (fixed by setup_inputs)
#define NP 8192      // pred vertices
#define NG 12000     // gt vertices
#define NFP 16384    // pred faces
#define NFG 24000    // gt faces
#define EPSF 1e-6f

// uniform grid for NN: 16^3 cells over [0,1]^3, ~3 gt / ~2 pred per cell
#define GR 16
#define NC (GR*GR*GR)        // 4096
#define HCELL 0.0625f        // 1/16, exact power of two
#define QL 16                // lanes cooperating per NN query (proven best)

// D1: 4 fat blocks (grid build x2, CSR build x2). No face atomics anywhere.
#define D1_BLOCKS 4

// D2 (1024-thr): query blocks (proven ~free) + gt-normal gather blocks
#define QPBLK 64
#define PQB (NP / QPBLK)                          // 128
#define GQB ((NG + QPBLK - 1) / QPBLK)            // 188
#define GGB ((NG + 1023) / 1024)                  // 12 gt-gather blocks
#define D2_BLOCKS (PQB + GQB + GGB)               // 328

// LDS staging capacities for queries (overflow -> correct global fallback)
#define CAPP  4608           // points (float4) = 73728 B
#define CWCAP 1312           // cstart window entries

// D3: per-vertex epilogue (pred CSR gather inlined) + combine
#define FIN_BLOCKS (NP / 256)                     // 32

// ---- workspace layout (bytes) ----
static constexpr size_t OFF_STARTP  = 0;        // (NC+1) u32, [NC]=NP
static constexpr size_t OFF_STARTG  = 16640;    // (NC+1) u32, [NC]=NG
static constexpr size_t OFF_SORTP   = 33280;    // 8192  float4 (x,y,z,idx-bits)
static constexpr size_t OFF_SORTG   = 164352;   // 12000 float4
static constexpr size_t OFF_GTN     = 356352;   // NG*3 f32 gt normals (plain stores)
static constexpr size_t OFF_ISTARTP = 500352;   // (NP+1) u32 CSR starts (pred)
static constexpr size_t OFF_IRECP   = 533136;   // 3*NFP u32 incidence records
static constexpr size_t OFF_ISTARTG = 729744;   // (NG+1) u32 CSR starts (gt)
static constexpr size_t OFF_IRECG   = 777760;   // 3*NFG u32 incidence records
static constexpr size_t OFF_NEAR    = 1065760;  // NP i32 nearest gt (original idx)
static constexpr size_t OFF_ACCUM   = 1098528;  // 8 f32 global accumulators
static constexpr size_t OFF_DONE    = 1098560;  // 1 u32 done-counter

__device__ __forceinline__ int cell_of(float x) {
    int c = (int)(x * (float)GR);
    return min(max(c, 0), GR - 1);
}

// One block builds one point set: histogram -> shuffle scan -> start[] ->
// scatter into cell-sorted order via LDS cursor table. (Proven cheap.)
__device__ __forceinline__ void build_cells(const float* __restrict__ pts, int n,
                                            unsigned* __restrict__ start,
                                            float4* __restrict__ sorted,
                                            unsigned* h, unsigned* wsum) {
    int t = threadIdx.x;                 // 0..1023
    int lane = t & 63, wid = t >> 6;     // 16 waves
    for (int i = t; i < NC; i += 1024) h[i] = 0u;
    __syncthreads();
    for (int i = t; i < n; i += 1024) {
        int c = (cell_of(pts[3*i+2]) * GR + cell_of(pts[3*i+1])) * GR + cell_of(pts[3*i]);
        atomicAdd(&h[c], 1u);
    }
    __syncthreads();
    unsigned a0 = h[4*t], a1 = h[4*t+1], a2 = h[4*t+2], a3 = h[4*t+3];
    unsigned tsum = a0 + a1 + a2 + a3;
    unsigned x = tsum;
    #pragma unroll
    for (int off = 1; off < 64; off <<= 1) {
        unsigned y = __shfl_up(x, off, 64);
        if (lane >= off) x += y;
    }
    if (lane == 63) wsum[wid] = x;       // wave totals
    __syncthreads();
    if (t < 16) {                        // scan 16 wave totals inside wave 0
        unsigned w = wsum[t];
        #pragma unroll
        for (int off = 1; off < 16; off <<= 1) {
            unsigned y = __shfl_up(w, off, 64);
            if (t >= off) w += y;
        }
        wsum[t] = w;                     // inclusive
    }
    __syncthreads();
    unsigned base = (wid ? wsum[wid-1] : 0u) + (x - tsum);  // exclusive prefix
    unsigned e0 = base, e1 = base + a0, e2 = base + a0 + a1, e3 = base + a0 + a1 + a2;
    start[4*t] = e0; start[4*t+1] = e1; start[4*t+2] = e2; start[4*t+3] = e3;
    h[4*t] = e0; h[4*t+1] = e1; h[4*t+2] = e2; h[4*t+3] = e3;  // reuse as cursor
    __syncthreads();
    for (int i = t; i < n; i += 1024) {
        float px = pts[3*i], py = pts[3*i+1], pz = pts[3*i+2];
        int c = (cell_of(pz) * GR + cell_of(py)) * GR + cell_of(px);
        unsigned pos = atomicAdd(&h[c], 1u);
        sorted[pos] = make_float4(px, py, pz, __int_as_float(i));
    }
    if (t == 0) start[NC] = (unsigned)n;   // end sentinel
}

// One block builds a vertex->incidence CSR for one mesh: LDS histogram over
// K*1024 vertex bins -> shuffle scan -> istart[] -> scatter incidence records
// ((fid<<2)|slot) via LDS cursors. Same proven machinery as build_cells,
// different bins. Replaces the 560K-float-atomic scatter (the measured 47us
// wall of round 7) with deterministic gather data.
template<int K>
__device__ void build_csr(const int* __restrict__ f, int nf, int nv,
                          unsigned* __restrict__ istart,
                          unsigned* __restrict__ irec,
                          unsigned* h, unsigned* wsum) {
    int t = threadIdx.x;
    int lane = t & 63, wid = t >> 6;
    const int nbins = K * 1024;
    for (int i = t; i < nbins; i += 1024) h[i] = 0u;
    __syncthreads();
    for (int i = t; i < 3 * nf; i += 1024) atomicAdd(&h[f[i]], 1u);
    __syncthreads();
    unsigned a[K];
    unsigned tsum = 0;
    #pragma unroll
    for (int k = 0; k < K; ++k) { a[k] = h[K*t + k]; tsum += a[k]; }
    unsigned x = tsum;
    #pragma unroll
    for (int off = 1; off < 64; off <<= 1) {
        unsigned y = __shfl_up(x, off, 64);
        if (lane >= off) x += y;
    }
    if (lane == 63) wsum[wid] = x;
    __syncthreads();
    if (t < 16) {
        unsigned w = wsum[t];
        #pragma unroll
        for (int off = 1; off < 16; off <<= 1) {
            unsigned y = __shfl_up(w, off, 64);
            if (t >= off) w += y;
        }
        wsum[t] = w;
    }
    __syncthreads();
    unsigned run = (wid ? wsum[wid-1] : 0u) + (x - tsum);   // exclusive prefix
    #pragma unroll
    for (int k = 0; k < K; ++k) {
        int idx = K*t + k;
        if (idx <= nv) istart[idx] = run;
        h[idx] = run;                    // cursor
        run += a[k];
    }
    if (t == 0) istart[nv] = (unsigned)(3 * nf);   // sentinel (all idx < nv)
    __syncthreads();
    for (int i = t; i < nf; i += 1024) {
        int i0 = f[3*i], i1 = f[3*i+1], i2 = f[3*i+2];
        unsigned p0 = atomicAdd(&h[i0], 1u); irec[p0] = ((unsigned)i << 2) | 0u;
        unsigned p1 = atomicAdd(&h[i1], 1u); irec[p1] = ((unsigned)i << 2) | 1u;
        unsigned p2 = atomicAdd(&h[i2], 1u); irec[p2] = ((unsigned)i << 2) | 2u;
    }
}

// Dispatch 1 (4 blocks): b0/b1 grid builds, b2 pred CSR (+accum zero), b3 gt CSR.
__global__ __launch_bounds__(1024) void build_kernel(const float* __restrict__ pred,
                                                     const float* __restrict__ gt,
                                                     const int* __restrict__ pf,
                                                     const int* __restrict__ gf,
                                                     unsigned* __restrict__ startP,
                                                     unsigned* __restrict__ startG,
                                                     float4* __restrict__ sortP,
                                                     float4* __restrict__ sortG,
                                                     unsigned* __restrict__ istartP,
                                                     unsigned* __restrict__ irecP,
                                                     unsigned* __restrict__ istartG,
                                                     unsigned* __restrict__ irecG,
                                                     float* __restrict__ accum,
                                                     unsigned* __restrict__ done) {
    __shared__ unsigned h[12288];        // 48 KB: max role (gt CSR, 12*1024 bins)
    __shared__ unsigned wsum[16];
    int b = blockIdx.x, t = threadIdx.x;
    if (b == 0) {
        build_cells(pred, NP, startP, sortP, h, wsum);
    } else if (b == 1) {
        build_cells(gt, NG, startG, sortG, h, wsum);
    } else if (b == 2) {
        if (t < 8) accum[t] = 0.0f;      // D2 touches accum only after D1 ends
        if (t == 8) *done = 0u;
        build_csr<8>(pf, NFP, NP, istartP, irecP, h, wsum);
    } else {
        build_csr<12>(gf, NFG, NG, istartG, irecG, h, wsum);
    }
}

__device__ __forceinline__ float wave_sum(float x) {
    #pragma unroll
    for (int o = 32; o > 0; o >>= 1) x += __shfl_down(x, o, 64);
    return x;
}

__device__ __forceinline__ unsigned long long u64min(unsigned long long a,
                                                     unsigned long long b) {
    return a < b ? a : b;
}

__device__ __forceinline__ unsigned long long pack_key(float px, float py, float pz,
                                                       float4 q) {
    float ddx = px - q.x, ddy = py - q.y, ddz = pz - q.z;
    float d2 = fmaf(ddx, ddx, fmaf(ddy, ddy, ddz*ddz));
    return ((unsigned long long)__float_as_uint(d2) << 32) |
           (unsigned)__float_as_int(q.w);
}

// 16-lane group NN (r=1: 27 cells over 16 lanes, LDS-staged window; proven
// ~free in round 7). r>=2 (~1e-4 of queries) and unstaged blocks use global.
__device__ unsigned long long group_nn(int lane, float px, float py, float pz,
                                       const float4* __restrict__ Sg,
                                       const unsigned* __restrict__ CSg,
                                       const float4* Sl, const unsigned* CSl,
                                       int c_lo, unsigned p_lo, bool staged) {
    int cx = cell_of(px), cy = cell_of(py), cz = cell_of(pz);
    unsigned long long best = 0xFFFFFFFFFFFFFFFFULL;
    {   // ---- r = 1: 27 cells across 16 lanes ----
        unsigned long long lb = 0xFFFFFFFFFFFFFFFFULL;
        for (int k = lane; k < 27; k += QL) {
            int z = cz + k / 9 - 1, y = cy + (k % 9) / 3 - 1, x = cx + k % 3 - 1;
            if (((unsigned)z < GR) & ((unsigned)y < GR) & ((unsigned)x < GR)) {
                int c = (z * GR + y) * GR + x;
                if (staged) {
                    unsigned s0 = CSl[c - c_lo];
                    unsigned s1 = CSl[c + 1 - c_lo];
                    for (unsigned u = s0; u < s1; ++u)
                        lb = u64min(lb, pack_key(px, py, pz, Sl[u - p_lo]));
                } else {
                    unsigned s0 = CSg[c];
                    unsigned s1 = CSg[c + 1];
                    for (unsigned u = s0; u < s1; ++u)
                        lb = u64min(lb, pack_key(px, py, pz, Sg[u]));
                }
            }
        }
        best = lb;
        #pragma unroll
        for (int m = 1; m < QL; m <<= 1)
            best = u64min(best, (unsigned long long)__shfl_xor((long long)best, m, 64));
        bool covered = (cx - 1 <= 0) & (cx + 1 >= GR - 1) &
                       (cy - 1 <= 0) & (cy + 1 >= GR - 1) &
                       (cz - 1 <= 0) & (cz + 1 >= GR - 1);
        float blo = 1.0e30f;
        if (cx - 1 > 0)      blo = fminf(blo, px - (float)(cx - 1) * HCELL);
        if (cx + 1 < GR - 1) blo = fminf(blo, (float)(cx + 2) * HCELL - px);
        if (cy - 1 > 0)      blo = fminf(blo, py - (float)(cy - 1) * HCELL);
        if (cy + 1 < GR - 1) blo = fminf(blo, (float)(cy + 2) * HCELL - py);
        if (cz - 1 > 0)      blo = fminf(blo, pz - (float)(cz - 1) * HCELL);
        if (cz + 1 < GR - 1) blo = fminf(blo, (float)(cz + 2) * HCELL - pz);
        float bd2 = __uint_as_float((unsigned)(best >> 32));
        if (covered || (bd2 <= blo * blo)) return best;   // NaN -> expand
    }
    for (int r = 2; ; ++r) {   // ---- cold global path ----
        int w = 2 * r + 1;
        int nrows = w * w;
        int x0 = max(cx - r, 0), x1 = min(cx + r, GR - 1);
        unsigned long long lb = 0xFFFFFFFFFFFFFFFFULL;
        for (int k = lane; k < nrows; k += QL) {
            int z = cz + k / w - r, y = cy + k % w - r;
            if (z >= 0 && z < GR && y >= 0 && y < GR) {
                int rowbase = (z * GR + y) * GR;
                unsigned s0 = CSg[rowbase + x0];
                unsigned s1 = CSg[rowbase + x1 + 1];
                for (unsigned u = s0; u < s1; ++u)
                    lb = u64min(lb, pack_key(px, py, pz, Sg[u]));
            }
        }
        best = u64min(best, lb);
        #pragma unroll
        for (int m = 1; m < QL; m <<= 1)
            best = u64min(best, (unsigned long long)__shfl_xor((long long)best, m, 64));
        bool covered = (cx - r <= 0) & (cx + r >= GR - 1) &
                       (cy - r <= 0) & (cy + r >= GR - 1) &
                       (cz - r <= 0) & (cz + r >= GR - 1);
        if (covered) break;
        float blo = 1.0e30f;
        if (cx - r > 0)      blo = fminf(blo, px - (float)(cx - r) * HCELL);
        if (cx + r < GR - 1) blo = fminf(blo, (float)(cx + r + 1) * HCELL - px);
        if (cy - r > 0)      blo = fminf(blo, py - (float)(cy - r) * HCELL);
        if (cy + r < GR - 1) blo = fminf(blo, (float)(cy + r + 1) * HCELL - py);
        if (cz - r > 0)      blo = fminf(blo, pz - (float)(cz - r) * HCELL);
        if (cz + r < GR - 1) blo = fminf(blo, (float)(cz + r + 1) * HCELL - pz);
        float bd2 = __uint_as_float((unsigned)(best >> 32));
        if (bd2 <= blo * blo) break;
    }
    return best;
}

// Dispatch 2 (1024-thr blocks):
//   [0,128)    pred->gt query blocks (LDS-staged gt window)
//   [128,316)  gt->pred query blocks (LDS-staged pred window)
//   [316,328)  gt-normal CSR gather: per gt vertex, recompute incident face
//              normals in registers, plain-store gtn. Zero atomics.
__global__ __launch_bounds__(1024) void query_gather_kernel(const float* __restrict__ gt,
                                                            const int* __restrict__ gf,
                                                            const float4* __restrict__ sortP,
                                                            const float4* __restrict__ sortG,
                                                            const unsigned* __restrict__ startP,
                                                            const unsigned* __restrict__ startG,
                                                            const unsigned* __restrict__ istartG,
                                                            const unsigned* __restrict__ irecG,
                                                            float* __restrict__ gtn,
                                                            int* __restrict__ nearestIdx,
                                                            float* __restrict__ accum) {
    __shared__ float4 lpts[CAPP];      // 73728 B
    __shared__ unsigned lcs[CWCAP];    // 5248 B
    __shared__ float qacc;
    __shared__ int s_info[4];          // c_lo, p_lo, np, +-cw
    int b = blockIdx.x, t = threadIdx.x;

    if (b >= PQB + GQB) {
        // ---- gt-normal gather ----
        int v = (b - PQB - GQB) * 1024 + t;
        if (v < NG) {
            unsigned s = istartG[v], e = istartG[v+1];
            float nx = 0.f, ny = 0.f, nz = 0.f;
            for (unsigned u = s; u < e; ++u) {
                int fid = (int)(irecG[u] >> 2);
                int i0 = gf[3*fid], i1 = gf[3*fid+1], i2 = gf[3*fid+2];
                float ax = gt[3*i0], ay = gt[3*i0+1], az = gt[3*i0+2];
                float bx = gt[3*i1], by = gt[3*i1+1], bz = gt[3*i1+2];
                float cx = gt[3*i2], cy = gt[3*i2+1], cz = gt[3*i2+2];
                float ux = bx-ax, uy = by-ay, uz = bz-az;
                float wx = cx-ax, wy = cy-ay, wz = cz-az;
                nx += uy*wz - uz*wy; ny += uz*wx - ux*wz; nz += ux*wy - uy*wx;
            }
            gtn[3*v] = nx; gtn[3*v+1] = ny; gtn[3*v+2] = nz;
        }
        return;
    }

    // ---- query blocks (proven ~free in round 7) ----
    bool is_pred = (b < PQB);
    const float4*   Q  = is_pred ? sortP  : sortG;
    const float4*   S  = is_pred ? sortG  : sortP;
    const unsigned* CS = is_pred ? startG : startP;
    int qbase = (is_pred ? b : (b - PQB)) * QPBLK;
    int nq = min(QPBLK, (is_pred ? NP : NG) - qbase);

    if (t == 0) {
        qacc = 0.0f;
        float4 qf = Q[qbase], ql = Q[qbase + nq - 1];
        int z_lo = cell_of(qf.z), z_hi = cell_of(ql.z);
        int c_lo  = max(z_lo - 1, 0) * (GR * GR);
        int c_end = min(z_hi + 2, GR) * (GR * GR);   // inclusive cstart idx
        int cw = c_end - c_lo + 1;
        unsigned p_lo = CS[c_lo], p_hi = CS[c_end];
        int np = (int)(p_hi - p_lo);
        bool ok = (cw <= CWCAP) && (np <= CAPP);
        s_info[0] = c_lo; s_info[1] = (int)p_lo; s_info[2] = np;
        s_info[3] = ok ? cw : -cw;
    }
    __syncthreads();
    int c_lo = s_info[0];
    unsigned p_lo = (unsigned)s_info[1];
    int np = s_info[2];
    int cw = s_info[3];
    bool staged = (cw > 0);
    if (staged) {
        for (int i = t; i < np; i += 1024) lpts[i] = S[p_lo + i];
        for (int i = t; i < cw; i += 1024) lcs[i]  = CS[c_lo + i];
    }
    __syncthreads();

    int lane = t & (QL - 1), group = t >> 4;     // group 0..63
    float r0 = 0.0f;
    if (group < nq) {
        int qid = qbase + group;
        float4 P = Q[qid];
        unsigned long long key = group_nn(lane, P.x, P.y, P.z, S, CS,
                                          lpts, lcs, c_lo, p_lo, staged);
        if (lane == 0) {
            r0 = __uint_as_float((unsigned)(key >> 32));
            if (is_pred)
                nearestIdx[__float_as_int(P.w)] = (int)(unsigned)(key & 0xffffffffu);
        }
    }
    r0 = wave_sum(r0);
    if ((t & 63) == 0) atomicAdd(&qacc, r0);
    __syncthreads();
    if (t == 0) atomicAdd(&accum[is_pred ? 0 : 6], qacc);
}

// Dispatch 3: per-vertex epilogue with the pred CSR gather INLINED (pnn/nsum/
// deg computed in registers from adjacency; those global arrays no longer
// exist). Last block (done-counter) combines.
__global__ __launch_bounds__(256) void finish_kernel(const float* __restrict__ pred,
                                                     const float* __restrict__ relpos,
                                                     const int* __restrict__ label,
                                                     const int* __restrict__ pf,
                                                     const unsigned* __restrict__ istartP,
                                                     const unsigned* __restrict__ irecP,
                                                     const float* __restrict__ gtn,
                                                     const int* __restrict__ nearestIdx,
                                                     float* __restrict__ accum,
                                                     unsigned* __restrict__ done,
                                                     float* __restrict__ out) {
    int v = blockIdx.x * 256 + threadIdx.x;     // < 8192 exact
    float px = pred[3*v], py = pred[3*v+1], pz = pred[3*v+2];
    int nearest = nearestIdx[v];

    // ---- pred CSR gather: face normals + laplacian neighbor sums ----
    unsigned s = istartP[v], e = istartP[v+1];
    float ax_ = 0.f, ay_ = 0.f, az_ = 0.f;          // pnn accum
    float nsx = 0.f, nsy = 0.f, nsz = 0.f;          // nsum accum
    for (unsigned u = s; u < e; ++u) {
        unsigned rec = irecP[u];
        int fid = (int)(rec >> 2), slot = (int)(rec & 3u);
        int i0 = pf[3*fid], i1 = pf[3*fid+1], i2 = pf[3*fid+2];
        float Ax = pred[3*i0], Ay = pred[3*i0+1], Az = pred[3*i0+2];
        float Bx = pred[3*i1], By = pred[3*i1+1], Bz = pred[3*i1+2];
        float Cx = pred[3*i2], Cy = pred[3*i2+1], Cz = pred[3*i2+2];
        float ux = Bx-Ax, uy = By-Ay, uz = Bz-Az;
        float wx = Cx-Ax, wy = Cy-Ay, wz = Cz-Az;
        ax_ += uy*wz - uz*wy; ay_ += uz*wx - ux*wz; az_ += ux*wy - uy*wx;
        if (slot == 0)      { nsx += Bx+Cx; nsy += By+Cy; nsz += Bz+Cz; }
        else if (slot == 1) { nsx += Cx+Ax; nsy += Cy+Ay; nsz += Cz+Az; }
        else                { nsx += Ax+Bx; nsy += Ay+By; nsz += Az+Bz; }
    }
    float d = fmaxf(2.0f * (float)(e - s), 1.0f);   // deg (2 per incidence)

    // normal consistency (normalize both accumulators on the fly)
    float an = fmaxf(sqrtf(ax_*ax_ + ay_*ay_ + az_*az_), EPSF);
    float gx = gtn[3*nearest], gy = gtn[3*nearest+1], gz = gtn[3*nearest+2];
    float gn = fmaxf(sqrtf(gx*gx + gy*gy + gz*gz), EPSF);
    float nx = ax_/an - gx/gn, ny = ay_/an - gy/gn, nz = az_/an - gz/gn;
    float sse = nx*nx + ny*ny + nz*nz;

    // laplacian
    float lx = nsx/d - px, ly = nsy/d - py, lz = nsz/d - pz;
    float lapn = sqrtf(lx*lx + ly*ly + lz*lz);

    // grid-sample target (nearest, align_corners=True, zeros padding)
    int ix = (int)rintf(px * 95.0f), iy = (int)rintf(py * 95.0f), iz = (int)rintf(pz * 95.0f);
    bool inb = (ix >= 0) & (ix < 96) & (iy >= 0) & (iy < 96) & (iz >= 0) & (iz < 96);
    int ixc = min(max(ix, 0), 95), iyc = min(max(iy, 0), 95), izc = min(max(iz, 0), 95);
    bool pos = inb && (label[(izc*96 + iyc)*96 + ixc] == 1);

    float p = fminf(fmaxf(relpos[v], EPSF), 1.0f - EPSF);
    float om = 1.0f - p;
    float pcnt = 0.0f, sx = 0.0f, sy = 0.0f;
    if (pos) { pcnt = 1.0f; sx = om*om*logf(p); }
    else     { sy = p*p*logf(om); }

    float r1 = wave_sum(sse), r2 = wave_sum(lapn), r3 = wave_sum(pcnt);
    float r4 = wave_sum(sx),  r5 = wave_sum(sy);
    __shared__ float bsum[5];
    __shared__ bool isLast;
    if (threadIdx.x < 5) bsum[threadIdx.x] = 0.0f;
    __syncthreads();
    if ((threadIdx.x & 63) == 0) {
        atomicAdd(&bsum[0], r1); atomicAdd(&bsum[1], r2); atomicAdd(&bsum[2], r3);
        atomicAdd(&bsum[3], r4); atomicAdd(&bsum[4], r5);
    }
    __syncthreads();
    if (threadIdx.x == 0) {
        atomicAdd(&accum[1], bsum[0]); atomicAdd(&accum[2], bsum[1]);
        atomicAdd(&accum[3], bsum[2]); atomicAdd(&accum[4], bsum[3]);
        atomicAdd(&accum[5], bsum[4]);
        __threadfence();                         // publish before done-count
        unsigned prev = atomicAdd(done, 1u);
        isLast = (prev == FIN_BLOCKS - 1);
    }
    __syncthreads();
    if (isLast && threadIdx.x == 0) {
        __threadfence();
        float sum_row = __hip_atomic_load(&accum[0], __ATOMIC_RELAXED, __HIP_MEMORY_SCOPE_AGENT);
        float sse_t   = __hip_atomic_load(&accum[1], __ATOMIC_RELAXED, __HIP_MEMORY_SCOPE_AGENT);
        float lap_t   = __hip_atomic_load(&accum[2], __ATOMIC_RELAXED, __HIP_MEMORY_SCOPE_AGENT);
        float pc      = __hip_atomic_load(&accum[3], __ATOMIC_RELAXED, __HIP_MEMORY_SCOPE_AGENT);
        float SX      = __hip_atomic_load(&accum[4], __ATOMIC_RELAXED, __HIP_MEMORY_SCOPE_AGENT);
        float SY      = __hip_atomic_load(&accum[5], __ATOMIC_RELAXED, __HIP_MEMORY_SCOPE_AGENT);
        float sum_col = __hip_atomic_load(&accum[6], __ATOMIC_RELAXED, __HIP_MEMORY_SCOPE_AGENT);
        float tot = (float)NP;
        float alpha = (tot - pc) / (tot + EPSF);
        float spatial = (-alpha * SX - (1.0f - alpha) * SY) / (tot + EPSF);
        float distance = sum_row / (float)NP + sum_col / (float)NG;
        float normal = sse_t / (float)(NP * 3);
        float lapm = lap_t / (float)NP;
        out[0] = spatial + 1.0f * distance + 0.01f * normal + 0.1f * lapm;
    }
}

extern "C" void kernel_launch(void* const* d_in, const int* in_sizes, int n_in,
                              void* d_out, int out_size, void* d_ws, size_t ws_size,
                              hipStream_t stream) {
    const float* pred   = (const float*)d_in[0];   // [8192,3]
    const float* relpos = (const float*)d_in[1];   // [8192]
    const float* gt     = (const float*)d_in[2];   // [12000,3]
    const int*   pfaces = (const int*)d_in[3];     // [16384,3]
    const int*   gfaces = (const int*)d_in[4];     // [24000,3]
    const int*   label  = (const int*)d_in[5];     // [1,1,96,96,96]
    float* out = (float*)d_out;

    char* ws = (char*)d_ws;
    unsigned* startP  = (unsigned*)(ws + OFF_STARTP);
    unsigned* startG  = (unsigned*)(ws + OFF_STARTG);
    float4*   sortP   = (float4*)(ws + OFF_SORTP);
    float4*   sortG   = (float4*)(ws + OFF_SORTG);
    float*    gtn     = (float*)(ws + OFF_GTN);
    unsigned* istartP = (unsigned*)(ws + OFF_ISTARTP);
    unsigned* irecP   = (unsigned*)(ws + OFF_IRECP);
    unsigned* istartG = (unsigned*)(ws + OFF_ISTARTG);
    unsigned* irecG   = (unsigned*)(ws + OFF_IRECG);
    int*      nearest = (int*)(ws + OFF_NEAR);
    float*    accum   = (float*)(ws + OFF_ACCUM);
    unsigned* done    = (unsigned*)(ws + OFF_DONE);

    // d1: grid builds || CSR adjacency builds (+tiny accum zero). NO atomics
    //     on float data anywhere in the pipeline from here on.
    hipLaunchKernelGGL(build_kernel, dim3(D1_BLOCKS), dim3(1024), 0, stream,
                       pred, gt, pfaces, gfaces, startP, startG, sortP, sortG,
                       istartP, irecP, istartG, irecG, accum, done);
    // d2: LDS-windowed group NN (proven ~free) || gt-normal CSR gather
    hipLaunchKernelGGL(query_gather_kernel, dim3(D2_BLOCKS), dim3(1024), 0, stream,
                       gt, gfaces, sortP, sortG, startP, startG,
                       istartG, irecG, gtn, nearest, accum);
    // d3: per-vertex epilogue (pred gather inlined) + last-block combine
    hipLaunchKernelGGL(finish_kernel, dim3(FIN_BLOCKS), dim3(256), 0, stream,
                       pred, relpos, label, pfaces, istartP, irecP,
                       gtn, nearest, accum, done, out);
}